// Round 6
// baseline (404.381 us; speedup 1.0000x reference)
//
#include <hip/hip_runtime.h>
#include <hip/hip_bf16.h>

#define B_ 4096
#define T_ 128
#define F_ 64
#define H_ 32
#define G_ 128  // 4*H

using short8 = __attribute__((ext_vector_type(8))) short;
using f32x4  = __attribute__((ext_vector_type(4))) float;

#define MFMA16(Af, Bf, Cf) __builtin_amdgcn_mfma_f32_16x16x32_bf16((Af), (Bf), (Cf), 0, 0, 0)

__device__ __forceinline__ float sigmoid_f(float z) {
    return __builtin_amdgcn_rcpf(1.0f + __expf(-z));
}
// float -> bf16 bits (RNE via hardware cvt)
__device__ __forceinline__ unsigned short bfb(float f) {
    return __builtin_bit_cast(unsigned short, __float2bfloat16(f));
}

// TRANSPOSED recurrence: z^T[gate][batch] = MFMA(A = W^T/U^T, B = x^T/h^T).
//   lane = 16*g + c   (g = lane>>4, c = lane&15); c = BATCH column, rows = gate/hidden.
// Logical k-map (both operands, so HW k-permutation cancels — validated by round-4 pass):
//   p(g,i) = 4g + (i&3) + 16*(i>>2)       (used for all H=32-contraction operands)
//   natural 8g+i                          (used for F=64-contraction x/We chunks)
// D layout (verified): D[row = 4g + r][col = c].
//   Tile n, reg r  ->  gate index 16n+4g+r, batch c.
//   Gates: i = n(0,1), f = n(2,3), g = n(4,5), o = n(6,7); hidden j = 16jh + 4g + r.
// After gates, lane (g,c) holds h[j = 16jh+4g+r][batch c] = exactly the next step's
// B-fragment under p — ZERO LDS / cross-lane on the recurrence critical path.
// Out-proj: hfrag reinterpreted as A-frag == h[batch c][hidden p(g,i)], so
// MFMA(hfrag, Wout-B-frag-with-p-map) gives D[batch 4g+r][feat 16m+c] -> coalesced stores.
extern "C" __global__ __launch_bounds__(64, 1)
void lstm_ae(const float* __restrict__ x,
             const float* __restrict__ We,
             const float* __restrict__ Ue,
             const float* __restrict__ be,
             const float* __restrict__ Wd,
             const float* __restrict__ Ud,
             const float* __restrict__ bd,
             const float* __restrict__ Wout,
             const float* __restrict__ bout,
             float* __restrict__ out)
{
    const int lane = threadIdx.x;
    const int g = lane >> 4;
    const int c = lane & 15;
    const int b0 = blockIdx.x << 4;

    // ---------------- encoder weights as register-stationary A-fragments ----------------
    // A-frag: lane (g,c) elem i = M-row (16n + c), k = p(g,i) (or 8g+i for x chunks)
    short8 weF[8][2];   // We^T: K=64 -> 2 chunks of 32, natural k-map 8g+i
    short8 ueF[8];      // Ue^T: K=32, p-map
#pragma unroll
    for (int n = 0; n < 8; ++n) {
#pragma unroll
        for (int kc = 0; kc < 2; ++kc)
#pragma unroll
            for (int i = 0; i < 8; ++i)
                weF[n][kc][i] = (short)bfb(We[(kc * 32 + 8 * g + i) * G_ + 16 * n + c]);
#pragma unroll
        for (int i = 0; i < 8; ++i)
            ueF[n][i] = (short)bfb(Ue[(4 * g + (i & 3) + 16 * (i >> 2)) * G_ + 16 * n + c]);
    }
    // bias as C-operand: rows are gate indices -> reg r gets be[16n + 4g + r] (f32x4 load)
    f32x4 beC[8];
#pragma unroll
    for (int n = 0; n < 8; ++n)
        beC[n] = *(const f32x4*)(be + 16 * n + 4 * g);

    const float* xr = x + (size_t)(b0 + c) * (T_ * F_);
    const int xo = 8 * g;

    // state: hfrag = B-fragment of h^T (bf16), cs = fp32 cell state (j = 16jh + 4g + r)
    short8 hfrag = (short8)0;  // h0 = 0
    float cs[2][4];
#pragma unroll
    for (int jh = 0; jh < 2; ++jh)
#pragma unroll
        for (int r = 0; r < 4; ++r) cs[jh][r] = 0.f;

    // prefetch x_0: B-frag of x^T (batch col c, features kc*32 + 8g + i -> 8 consecutive)
    f32x4 xa = *(const f32x4*)(xr + xo);
    f32x4 xb = *(const f32x4*)(xr + xo + 4);
    f32x4 xc = *(const f32x4*)(xr + 32 + xo);
    f32x4 xd = *(const f32x4*)(xr + 36 + xo);

    // =============================== encoder scan ===============================
#pragma unroll 1
    for (int t = 0; t < T_; ++t) {
        short8 xf0, xf1;
#pragma unroll
        for (int i = 0; i < 4; ++i) {
            xf0[i]     = (short)bfb(xa[i]);
            xf0[4 + i] = (short)bfb(xb[i]);
            xf1[i]     = (short)bfb(xc[i]);
            xf1[4 + i] = (short)bfb(xd[i]);
        }
        if (t + 1 < T_) {  // prefetch next x row (hidden behind this step's compute)
            const float* xn = xr + (t + 1) * F_;
            xa = *(const f32x4*)(xn + xo);
            xb = *(const f32x4*)(xn + xo + 4);
            xc = *(const f32x4*)(xn + 32 + xo);
            xd = *(const f32x4*)(xn + 36 + xo);
        }

        // z^T tile n: x-part first (independent of h), Ue-part last (shortest h-chain)
        f32x4 acc[8];
#pragma unroll
        for (int n = 0; n < 8; ++n) {
            acc[n] = MFMA16(weF[n][0], xf0, beC[n]);
            acc[n] = MFMA16(weF[n][1], xf1, acc[n]);
            acc[n] = MFMA16(ueF[n], hfrag, acc[n]);
        }

        // gates: lane (g,c), (jh,r) -> hidden j = 16jh+4g+r, batch c. Pure lane-local.
#pragma unroll
        for (int jh = 0; jh < 2; ++jh)
#pragma unroll
            for (int r = 0; r < 4; ++r) {
                float iv = sigmoid_f(acc[0 + jh][r]);
                float fv = sigmoid_f(acc[2 + jh][r]);
                float gv = fmaxf(acc[4 + jh][r], 0.f);
                float ov = sigmoid_f(acc[6 + jh][r]);
                float cc = fmaf(fv, cs[jh][r], iv * gv);
                cs[jh][r] = cc;
                float hv = ov * fmaxf(cc, 0.f);
                hfrag[4 * jh + r] = (short)bfb(hv);  // elem 4jh+r == k p(g,4jh+r)=16jh+4g+r
            }
    }

    // ================= decoder constant input zd^T = bd + Wd^T hT (once) =================
    short8 udF[8], woF[4];
    f32x4 zd[8], boC[4];
    {
        short8 wdF[8];
#pragma unroll
        for (int n = 0; n < 8; ++n)
#pragma unroll
            for (int i = 0; i < 8; ++i) {
                int pr = 4 * g + (i & 3) + 16 * (i >> 2);
                wdF[n][i] = (short)bfb(Wd[pr * G_ + 16 * n + c]);
                udF[n][i] = (short)bfb(Ud[pr * G_ + 16 * n + c]);
            }
#pragma unroll
        for (int m = 0; m < 4; ++m) {
#pragma unroll
            for (int i = 0; i < 8; ++i)
                woF[m][i] = (short)bfb(Wout[(4 * g + (i & 3) + 16 * (i >> 2)) * F_ + 16 * m + c]);
            float v = bout[16 * m + c];   // out-proj D cols = features -> splat per col
            f32x4 tb; tb[0] = v; tb[1] = v; tb[2] = v; tb[3] = v;
            boC[m] = tb;
        }
#pragma unroll
        for (int n = 0; n < 8; ++n) {
            f32x4 tb = *(const f32x4*)(bd + 16 * n + 4 * g);  // rows = gate idx
            zd[n] = MFMA16(wdF[n], hfrag, tb);   // hfrag == hT (B-frag) here
        }
    }

    // reset recurrent state for decoder
    hfrag = (short8)0;
#pragma unroll
    for (int jh = 0; jh < 2; ++jh)
#pragma unroll
        for (int r = 0; r < 4; ++r) cs[jh][r] = 0.f;

    float* ob[4];
#pragma unroll
    for (int r = 0; r < 4; ++r)
        ob[r] = out + (size_t)(b0 + 4 * g + r) * (T_ * F_) + c;

    // ==================== decoder scan + fused output projection ====================
#pragma unroll 1
    for (int t = 0; t < T_; ++t) {
        f32x4 acc[8];
#pragma unroll
        for (int n = 0; n < 8; ++n)
            acc[n] = MFMA16(udF[n], hfrag, zd[n]);  // z^T = zd^T + Ud^T h^T

#pragma unroll
        for (int jh = 0; jh < 2; ++jh)
#pragma unroll
            for (int r = 0; r < 4; ++r) {
                float iv = sigmoid_f(acc[0 + jh][r]);
                float fv = sigmoid_f(acc[2 + jh][r]);
                float gv = fmaxf(acc[4 + jh][r], 0.f);
                float ov = sigmoid_f(acc[6 + jh][r]);
                float cc = fmaf(fv, cs[jh][r], iv * gv);
                cs[jh][r] = cc;
                float hv = ov * fmaxf(cc, 0.f);
                hfrag[4 * jh + r] = (short)bfb(hv);
            }

        // out-proj: hfrag as A-frag (rows = batch c, k = p(g,i)) x Wout B-frag (p-map)
        // D[batch 4g+r][feat 16m+c] -> coalesced dword stores (off recurrence path)
        f32x4 oac[4];
#pragma unroll
        for (int m = 0; m < 4; ++m)
            oac[m] = MFMA16(hfrag, woF[m], boC[m]);
#pragma unroll
        for (int m = 0; m < 4; ++m)
#pragma unroll
            for (int r = 0; r < 4; ++r)
                ob[r][t * F_ + 16 * m] = oac[m][r];
    }
}

extern "C" void kernel_launch(void* const* d_in, const int* in_sizes, int n_in,
                              void* d_out, int out_size, void* d_ws, size_t ws_size,
                              hipStream_t stream) {
    (void)in_sizes; (void)n_in; (void)d_ws; (void)ws_size; (void)out_size;
    const float* x    = (const float*)d_in[0];
    const float* We   = (const float*)d_in[1];
    const float* Ue   = (const float*)d_in[2];
    const float* be   = (const float*)d_in[3];
    const float* Wd   = (const float*)d_in[4];
    const float* Ud   = (const float*)d_in[5];
    const float* bd   = (const float*)d_in[6];
    const float* Wout = (const float*)d_in[7];
    const float* bout = (const float*)d_in[8];
    float* out = (float*)d_out;

    dim3 grid(B_ / 16), block(64);
    hipLaunchKernelGGL(lstm_ae, grid, block, 0, stream,
                       x, We, Ue, be, Wd, Ud, bd, Wout, bout, out);
}

// Round 7
// 345.578 us; speedup vs baseline: 1.1702x; 1.1702x over previous
//
#include <hip/hip_runtime.h>
#include <hip/hip_bf16.h>

#define B_ 4096
#define T_ 128
#define F_ 64
#define H_ 32
#define G_ 128  // 4*H

using short8 = __attribute__((ext_vector_type(8))) short;
using f32x4  = __attribute__((ext_vector_type(4))) float;
using uint2v = __attribute__((ext_vector_type(2))) unsigned int;
using uint4v = __attribute__((ext_vector_type(4))) unsigned int;

#define MFMA16(Af, Bf, Cf) __builtin_amdgcn_mfma_f32_16x16x32_bf16((Af), (Bf), (Cf), 0, 0, 0)

__device__ __forceinline__ float sigmoid_f(float z) {
    return __builtin_amdgcn_rcpf(1.0f + __expf(-z));
}
__device__ __forceinline__ unsigned short bfb(float f) {
    return __builtin_bit_cast(unsigned short, __float2bfloat16(f));
}
__device__ __forceinline__ unsigned int pk(float a, float b) {
    return (unsigned int)bfb(a) | ((unsigned int)bfb(b) << 16);
}

// TRANSPOSED recurrence (p-map validated in round 6), GATE-SPLIT across 2 waves.
//   lane = 16*g + c (g=lane>>4, c=lane&15): c = batch col, rows = gate/hidden.
//   p(g,i) = 4g + (i&3) + 16*(i>>2)  (H=32 contraction operands, both sides -> HW perm cancels)
// Wave w (0,1) owns hidden half 16w..16w+15 = gate tiles n = 2q+w, q=0..3 (i,f,g,o):
//   per step per wave: 4 MFMAs + 12 sigmoids (half of the serial VALU work).
// D layout: D[row=4g+r][col=c] -> acc[q][r] = z[gate q, hidden 16w+4g+r][batch c]. Lane-local gates.
// h-exchange: lane packs its 4 bf16 (hidden 16w+4g+0..3, batch c) into 2 dwords ->
//   hx[t&1][c][8w+2g..+1]; one __syncthreads(); read other wave's 2 dwords; assemble full
//   B-frag (elems 0-3 = hidden 4g+r = wave0 half, elems 4-7 = 16+4g+r = wave1 half).
// Double-buffered on t&1 -> single barrier per step is race-free (waves stay within one barrier).
// Out-proj (decoder): full hfrag as A-frag x Wout B-frag (p-map); wave w does feat tiles m=2w,2w+1.
extern "C" __global__ __launch_bounds__(128, 1)
void lstm_ae(const float* __restrict__ x,
             const float* __restrict__ We,
             const float* __restrict__ Ue,
             const float* __restrict__ be,
             const float* __restrict__ Wd,
             const float* __restrict__ Ud,
             const float* __restrict__ bd,
             const float* __restrict__ Wout,
             const float* __restrict__ bout,
             float* __restrict__ out)
{
    const int lane = threadIdx.x & 63;
    const int w    = threadIdx.x >> 6;
    const int g    = lane >> 4;
    const int c    = lane & 15;
    const int b0   = blockIdx.x << 4;

    // exchange buffer: [buf][batch c][dword idx = hidden/2], stride 18 dwords (even -> b64 aligned)
    __shared__ __align__(16) unsigned int hx[2][16][18];

    // ---------------- encoder weights: A-fragments for this wave's 4 tiles ----------------
    short8 weF[4][2];   // We^T: K=64 -> 2 chunks, natural k-map 8g+i
    short8 ueF[4];      // Ue^T: K=32, p-map
    f32x4  beC[4];
#pragma unroll
    for (int q = 0; q < 4; ++q) {
        const int n = 2 * q + w;
#pragma unroll
        for (int kc = 0; kc < 2; ++kc)
#pragma unroll
            for (int i = 0; i < 8; ++i)
                weF[q][kc][i] = (short)bfb(We[(kc * 32 + 8 * g + i) * G_ + 16 * n + c]);
#pragma unroll
        for (int i = 0; i < 8; ++i)
            ueF[q][i] = (short)bfb(Ue[(4 * g + (i & 3) + 16 * (i >> 2)) * G_ + 16 * n + c]);
        beC[q] = *(const f32x4*)(be + 16 * n + 4 * g);
    }

    const float* xr = x + (size_t)(b0 + c) * (T_ * F_);
    const int xo = 8 * g;

    short8 hfrag = (short8)0;           // full h B-frag (both halves)
    float cs[4];                        // cell state: hidden 16w+4g+r, batch c
#pragma unroll
    for (int r = 0; r < 4; ++r) cs[r] = 0.f;

    f32x4 xa = *(const f32x4*)(xr + xo);
    f32x4 xb = *(const f32x4*)(xr + xo + 4);
    f32x4 xc = *(const f32x4*)(xr + 32 + xo);
    f32x4 xd = *(const f32x4*)(xr + 36 + xo);

    // =============================== encoder scan ===============================
#pragma unroll 1
    for (int t = 0; t < T_; ++t) {
        short8 xf0, xf1;
#pragma unroll
        for (int i = 0; i < 4; ++i) {
            xf0[i]     = (short)bfb(xa[i]);
            xf0[4 + i] = (short)bfb(xb[i]);
            xf1[i]     = (short)bfb(xc[i]);
            xf1[4 + i] = (short)bfb(xd[i]);
        }
        if (t + 1 < T_) {
            const float* xn = xr + (t + 1) * F_;
            xa = *(const f32x4*)(xn + xo);
            xb = *(const f32x4*)(xn + xo + 4);
            xc = *(const f32x4*)(xn + 32 + xo);
            xd = *(const f32x4*)(xn + 36 + xo);
        }

        f32x4 acc[4];
#pragma unroll
        for (int q = 0; q < 4; ++q) {
            acc[q] = MFMA16(weF[q][0], xf0, beC[q]);
            acc[q] = MFMA16(weF[q][1], xf1, acc[q]);
            acc[q] = MFMA16(ueF[q], hfrag, acc[q]);
        }

        float hv[4];
#pragma unroll
        for (int r = 0; r < 4; ++r) {
            float iv = sigmoid_f(acc[0][r]);
            float fv = sigmoid_f(acc[1][r]);
            float gv = fmaxf(acc[2][r], 0.f);
            float ov = sigmoid_f(acc[3][r]);
            float cc = fmaf(fv, cs[r], iv * gv);
            cs[r] = cc;
            hv[r] = ov * fmaxf(cc, 0.f);
        }
        uint2v own; own.x = pk(hv[0], hv[1]); own.y = pk(hv[2], hv[3]);
        *(uint2v*)&hx[t & 1][c][8 * w + 2 * g] = own;
        __syncthreads();
        uint2v oth = *(const uint2v*)&hx[t & 1][c][8 * (1 - w) + 2 * g];
        uint4v hb;
        hb.x = w ? oth.x : own.x;   // elems 0,1: hidden 4g+{0,1} (wave0 half)
        hb.y = w ? oth.y : own.y;   // elems 2,3: hidden 4g+{2,3}
        hb.z = w ? own.x : oth.x;   // elems 4,5: hidden 16+4g+{0,1} (wave1 half)
        hb.w = w ? own.y : oth.y;   // elems 6,7
        hfrag = __builtin_bit_cast(short8, hb);
    }

    // ============ decoder weights + constant input zd^T = bd + Wd^T hT (this wave's tiles) ============
    short8 udF[4], woF[2];
    f32x4  zd[4], boC[2];
    {
        short8 wdF[4];
#pragma unroll
        for (int q = 0; q < 4; ++q) {
            const int n = 2 * q + w;
#pragma unroll
            for (int i = 0; i < 8; ++i) {
                const int pr = 4 * g + (i & 3) + 16 * (i >> 2);
                wdF[q][i] = (short)bfb(Wd[pr * G_ + 16 * n + c]);
                udF[q][i] = (short)bfb(Ud[pr * G_ + 16 * n + c]);
            }
        }
#pragma unroll
        for (int mi = 0; mi < 2; ++mi) {
            const int m = 2 * w + mi;
#pragma unroll
            for (int i = 0; i < 8; ++i)
                woF[mi][i] = (short)bfb(Wout[(4 * g + (i & 3) + 16 * (i >> 2)) * F_ + 16 * m + c]);
            float v = bout[16 * m + c];
            f32x4 tb; tb[0] = v; tb[1] = v; tb[2] = v; tb[3] = v;
            boC[mi] = tb;
        }
#pragma unroll
        for (int q = 0; q < 4; ++q) {
            f32x4 tb = *(const f32x4*)(bd + 16 * (2 * q + w) + 4 * g);
            zd[q] = MFMA16(wdF[q], hfrag, tb);   // hfrag == full hT here
        }
    }

    // reset recurrent state
    hfrag = (short8)0;
#pragma unroll
    for (int r = 0; r < 4; ++r) cs[r] = 0.f;

    float* ob[4];
#pragma unroll
    for (int r = 0; r < 4; ++r)
        ob[r] = out + (size_t)(b0 + 4 * g + r) * (T_ * F_) + c;

    // ==================== decoder scan + fused output projection ====================
#pragma unroll 1
    for (int t = 0; t < T_; ++t) {
        f32x4 acc[4];
#pragma unroll
        for (int q = 0; q < 4; ++q)
            acc[q] = MFMA16(udF[q], hfrag, zd[q]);   // z^T = zd^T + Ud^T h^T (this wave's tiles)

        float hv[4];
#pragma unroll
        for (int r = 0; r < 4; ++r) {
            float iv = sigmoid_f(acc[0][r]);
            float fv = sigmoid_f(acc[1][r]);
            float gv = fmaxf(acc[2][r], 0.f);
            float ov = sigmoid_f(acc[3][r]);
            float cc = fmaf(fv, cs[r], iv * gv);
            cs[r] = cc;
            hv[r] = ov * fmaxf(cc, 0.f);
        }
        uint2v own; own.x = pk(hv[0], hv[1]); own.y = pk(hv[2], hv[3]);
        *(uint2v*)&hx[t & 1][c][8 * w + 2 * g] = own;
        __syncthreads();
        uint2v oth = *(const uint2v*)&hx[t & 1][c][8 * (1 - w) + 2 * g];
        uint4v hb;
        hb.x = w ? oth.x : own.x;
        hb.y = w ? oth.y : own.y;
        hb.z = w ? own.x : oth.x;
        hb.w = w ? own.y : oth.y;
        hfrag = __builtin_bit_cast(short8, hb);      // full h_t

        // out-proj: this wave stores feature tiles m = 2w, 2w+1 (off recurrence path)
#pragma unroll
        for (int mi = 0; mi < 2; ++mi) {
            f32x4 oac = MFMA16(hfrag, woF[mi], boC[mi]);
            const int m = 2 * w + mi;
#pragma unroll
            for (int r = 0; r < 4; ++r)
                ob[r][t * F_ + 16 * m] = oac[r];
        }
    }
}

extern "C" void kernel_launch(void* const* d_in, const int* in_sizes, int n_in,
                              void* d_out, int out_size, void* d_ws, size_t ws_size,
                              hipStream_t stream) {
    (void)in_sizes; (void)n_in; (void)d_ws; (void)ws_size; (void)out_size;
    const float* x    = (const float*)d_in[0];
    const float* We   = (const float*)d_in[1];
    const float* Ue   = (const float*)d_in[2];
    const float* be   = (const float*)d_in[3];
    const float* Wd   = (const float*)d_in[4];
    const float* Ud   = (const float*)d_in[5];
    const float* bd   = (const float*)d_in[6];
    const float* Wout = (const float*)d_in[7];
    const float* bout = (const float*)d_in[8];
    float* out = (float*)d_out;

    dim3 grid(B_ / 16), block(128);
    hipLaunchKernelGGL(lstm_ae, grid, block, 0, stream,
                       x, We, Ue, be, Wd, Ud, bd, Wout, bout, out);
}